// Round 9
// baseline (841.990 us; speedup 1.0000x reference)
//
#include <hip/hip_runtime.h>
#include <math.h>

#define NB 64
#define CO 512
#define NGATES 2048
#define INDIM 768
#define KTOT 1280
#define IMG 256
#define GS 16
#define EPSF 1e-4f
#define NCHUNK 8
#define CHUNK 160   // KTOT / NCHUNK

#define FMA2(A,S,V) {(A).x+=(S)*(V).x;(A).y+=(S)*(V).y;}

__device__ __forceinline__ float sigmoidf_(float x){ return 1.0f/(1.0f+expf(-x)); }

__device__ __forceinline__ float waveReduceSum(float v){
  #pragma unroll
  for (int off=32; off>0; off>>=1) v += __shfl_down(v, off, 64);
  return v;
}

// out[c][r] = in[r][c]; rows, cols multiples of 32
__global__ __launch_bounds__(256) void transpose_k(const float* __restrict__ in,
                                                   float* __restrict__ out,
                                                   int rows, int cols){
  __shared__ float tile[32][33];
  int bx = blockIdx.x*32, by = blockIdx.y*32;
  int tx = threadIdx.x, ty = threadIdx.y;
  #pragma unroll
  for (int i=ty;i<32;i+=8)
    tile[i][tx] = in[(size_t)(by+i)*cols + bx+tx];
  __syncthreads();
  #pragma unroll
  for (int i=ty;i<32;i+=8)
    out[(size_t)(bx+i)*rows + by+tx] = tile[tx][i];
}

// Fused lstm + params + filterbanks + glimpse contraction, w-split.
// Block (b, c, hw): hw = w-half. 384 blocks x 512 threads, ~62KB LDS
// -> 2 blocks/CU co-resident. FP orders identical to round 8.
__global__ __launch_bounds__(512, 4) void extlstm5_k(
    const float* __restrict__ imgs,  // [NB][2][3][IMG][IMG]
    int t,                           // step 0..15
    const float* __restrict__ partT, // [NCHUNK][NB][NGATES] gates of step t-1
    const float* __restrict__ b_ih,  // [NGATES]
    const float* __restrict__ b_hh,  // [NGATES]
    const float* __restrict__ Wg,    // [3][CO]
    const float* __restrict__ bg,    // [3]
    float* __restrict__ cbuf,        // [2][NB][CO] ping-pong cell state
    float* __restrict__ xp0,         // [KTOT][NB] partial (w-half 0) + h rows
    float* __restrict__ xp1)         // [KTOT][NB] partial (w-half 1), h rows 0
{
  __shared__ float hs[CO];
  __shared__ float gp[3];
  __shared__ float wred[8][4];
  __shared__ float prt[2][GS][4];
  __shared__ float rowinv[2][GS];
  __shared__ float fhT[256][16];     // [row][g] (broadcast reads, no pad)
  __shared__ float fws[GS][132];     // [g][w-local]
  __shared__ float g1[4][GS][132];   // partials; final in g1[0]

  const int bc = blockIdx.x;
  const int b = bc/6, cc = bc%6, c = cc>>1, hw = cc&1;
  const int t0 = threadIdx.x;
  const int q = t0>>6, lane = t0&63;
  float* xhP = hw ? xp1 : xp0;

  // ---- 1) h_t, c_t from previous step's gates (FP order == lstm2_k) ----
  if (t == 0){
    if (t0 < 256){ hs[t0]=0.f; hs[t0+256]=0.f; }
    if (c == 0){
      // zero h rows of BOTH partial buffers (each launch must re-init)
      xhP[(size_t)(INDIM+t0)*NB + b] = 0.f;
    }
  } else {
    const int u = t0;
    float gi=0.f,gf=0.f,gc=0.f,go=0.f;
    #pragma unroll
    for (int s2=0;s2<NCHUNK;s2++){
      const float* p = partT + ((size_t)s2*NB + b)*NGATES;  // coalesced in u
      gi += p[u];
      gf += p[512+u];
      gc += p[1024+u];
      go += p[1536+u];
    }
    gi += b_ih[u]      + b_hh[u];
    gf += b_ih[512+u]  + b_hh[512+u];
    gc += b_ih[1024+u] + b_hh[1024+u];
    go += b_ih[1536+u] + b_hh[1536+u];
    float cold = (t==1) ? 0.f
               : cbuf[(size_t)((t-1)&1)*NB*CO + (size_t)b*CO + u];
    float cnew = sigmoidf_(gf)*cold + sigmoidf_(gi)*tanhf(gc);
    float hnew = sigmoidf_(go)*tanhf(cnew);
    hs[u] = hnew;
    if (c == 0 && hw == 0){
      cbuf[(size_t)(t&1)*NB*CO + (size_t)b*CO + u] = cnew;
      xp0[(size_t)(INDIM+u)*NB + b] = hnew;   // xp1 h rows stay 0 from t==0
    }
  }
  __syncthreads();

  // ---- 2) glimpse params: 3 dot-products in one parallel pass ----
  {
    float hval = hs[t0];
    float p0 = Wg[0*CO+t0]*hval;
    float p1 = Wg[1*CO+t0]*hval;
    float p2 = Wg[2*CO+t0]*hval;
    p0 = waveReduceSum(p0);
    p1 = waveReduceSum(p1);
    p2 = waveReduceSum(p2);
    if (lane==0){ wred[q][0]=p0; wred[q][1]=p1; wred[q][2]=p2; }
    __syncthreads();
    if (t0 < 3){
      float s = 0.f;
      #pragma unroll
      for (int w8=0; w8<8; w8++) s += wred[w8][t0];
      gp[t0] = tanhf(s + bg[t0]);
    }
    __syncthreads();
  }

  // ---- 3) filterbanks: waves 0-3 fb0 (full fhT), waves 4-7 fb1 (store half)
  {
    float delta = gp[2];
    float dabs  = fabsf(delta);
    float deltas = ((float)IMG/(float)GS) * (1.0f - dabs);
    float gamma  = expf(1.0f - 2.0f*dabs);
    float inv_g  = 1.0f/gamma;
    float pref   = 1.0f/(3.14159265358979f*gamma);
    const int fb = t0 >> 8;           // 0: waves 0-3, 1: waves 4-7
    const int p  = t0 & 255;
    const int wid = q & 3;
    float fi = (float)p;
    float fx[GS];
    float centers = 255.0f*0.5f*(gp[fb]+1.0f);
    #pragma unroll
    for (int g=0; g<GS; g++){
      float mu = centers + deltas*((float)g - 7.5f);
      float d  = (fi - mu)*inv_g;
      fx[g] = pref/(1.0f + d*d);
    }
    #pragma unroll
    for (int g=0; g<GS; g++){
      float sv = waveReduceSum(fx[g]);
      if (lane==0) prt[fb][g][wid]=sv;
    }
    __syncthreads();
    if (t0 < 32){
      int f2 = t0 >> 4, g = t0 & 15;
      rowinv[f2][g] = 1.0f/((((prt[f2][g][0]+prt[f2][g][1])+prt[f2][g][2])+prt[f2][g][3]) + EPSF);
    }
    __syncthreads();
    if (fb==0){
      #pragma unroll
      for (int g=0; g<GS; g++) fhT[p][g] = fx[g]*rowinv[0][g];
    } else if ((p>>7) == hw){
      const int pl = p & 127;
      #pragma unroll
      for (int g=0; g<GS; g++) fws[g][pl] = fx[g]*rowinv[1][g];
    }
    __syncthreads();
  }

  // ---- 4) phase 1: wave q owns hh [q*32,q*32+32); lane owns 2 w cols ----
  {
    const float2* img2 = (const float2*)(imgs
        + (((size_t)b*2 + (t&1))*3 + c)*((size_t)IMG*IMG));
    float2 acc[GS];
    #pragma unroll
    for (int g=0; g<GS; g++){ acc[g].x=0.f; acc[g].y=0.f; }
    const int row0 = q*32;
    const int wbase = hw*64 + lane;
    #pragma unroll 8
    for (int i=0; i<32; i++){
      const int row = row0 + i;
      float2 v = img2[(size_t)row*128 + wbase];        // coalesced 512B/wave
      const float4* fq = (const float4*)&fhT[row][0];  // wave-uniform broadcast
      float4 f0=fq[0], f1=fq[1], f2=fq[2], f3=fq[3];
      FMA2(acc[0], f0.x, v); FMA2(acc[1], f0.y, v); FMA2(acc[2], f0.z, v); FMA2(acc[3], f0.w, v);
      FMA2(acc[4], f1.x, v); FMA2(acc[5], f1.y, v); FMA2(acc[6], f1.z, v); FMA2(acc[7], f1.w, v);
      FMA2(acc[8], f2.x, v); FMA2(acc[9], f2.y, v); FMA2(acc[10],f2.z, v); FMA2(acc[11],f2.w, v);
      FMA2(acc[12],f3.x, v); FMA2(acc[13],f3.y, v); FMA2(acc[14],f3.z, v); FMA2(acc[15],f3.w, v);
    }
    // reduce 8 wave-partials -> 4 (waves 4-7 add) -> 1 (all waves fold)
    if (q < 4){
      #pragma unroll
      for (int g=0; g<GS; g++) *(float2*)&g1[q][g][lane*2] = acc[g];
    }
    __syncthreads();
    if (q >= 4){
      #pragma unroll
      for (int g=0; g<GS; g++){
        float2 o = *(float2*)&g1[q-4][g][lane*2];
        o.x+=acc[g].x; o.y+=acc[g].y;
        *(float2*)&g1[q-4][g][lane*2] = o;
      }
    }
    __syncthreads();
    {
      #pragma unroll
      for (int gi2=0; gi2<2; gi2++){
        int g = q*2 + gi2;
        float2 s0 = *(float2*)&g1[0][g][lane*2];
        float2 s1 = *(float2*)&g1[1][g][lane*2];
        float2 s2 = *(float2*)&g1[2][g][lane*2];
        float2 s3 = *(float2*)&g1[3][g][lane*2];
        s0.x = ((s0.x+s1.x)+s2.x)+s3.x;
        s0.y = ((s0.y+s1.y)+s2.y)+s3.y;
        *(float2*)&g1[0][g][lane*2] = s0;
      }
    }
    __syncthreads();
  }

  // ---- 5) phase 2: this block's 128-ww partial, inner order == r8 half ----
  if (t0 < 256){
    int gg = t0 >> 4, kk = t0 & 15;
    const float4* grow = (const float4*)&g1[0][gg][0];
    const float4* frow = (const float4*)&fws[kk][0];
    float s = 0.f;
    #pragma unroll 8
    for (int j=0; j<32; j++){
      float4 gv = grow[j], fv = frow[j];
      s += gv.x*fv.x; s += gv.y*fv.y; s += gv.z*fv.z; s += gv.w*fv.w;
    }
    xhP[(size_t)(c*256 + t0)*NB + b] = s;
  }
}

// gates partial GEMM: partT[s][b][r] = sum_{k in chunk s} Wcat[k][r]*
// (xp0[k][b]+xp1[k][b]).  grid 512 = 64 row-tiles x 8 K-chunks.
__global__ __launch_bounds__(256) void gates6_k(
    const float* __restrict__ Wcat,  // [KTOT][NGATES]
    const float* __restrict__ xp0,   // [KTOT][NB]
    const float* __restrict__ xp1,   // [KTOT][NB]
    float* __restrict__ partT)       // [NCHUNK][NB][NGATES]
{
  __shared__ float tile[32][65];
  int s  = blockIdx.x & (NCHUNK-1);
  int rt = blockIdx.x >> 3;
  int wave = threadIdx.x >> 6, lane = threadIdx.x & 63;
  int r0 = rt*32 + wave*8;
  int c0 = s*CHUNK;
  const float* ap0 = xp0 + (size_t)c0*NB + lane;
  const float* ap1 = xp1 + (size_t)c0*NB + lane;
  const float* wp = Wcat + (size_t)c0*NGATES + r0;
  float acc[8];
  #pragma unroll
  for (int i=0;i<8;i++) acc[i]=0.f;
  #pragma unroll 4
  for (int k=0;k<CHUNK;k++){
    float a = ap0[(size_t)k*NB] + ap1[(size_t)k*NB];    // coalesced
    const float4* wr = (const float4*)(wp + (size_t)k*NGATES);
    float4 w0=wr[0], w1=wr[1];
    acc[0]+=w0.x*a; acc[1]+=w0.y*a; acc[2]+=w0.z*a; acc[3]+=w0.w*a;
    acc[4]+=w1.x*a; acc[5]+=w1.y*a; acc[6]+=w1.z*a; acc[7]+=w1.w*a;
  }
  #pragma unroll
  for (int i=0;i<8;i++) tile[wave*8+i][lane] = acc[i];
  __syncthreads();
  int b = threadIdx.x >> 2, qq = threadIdx.x & 3;
  float* dst = partT + ((size_t)s*NB + b)*NGATES + rt*32 + qq*8;
  float4 v0, v1;
  v0.x=tile[qq*8+0][b]; v0.y=tile[qq*8+1][b]; v0.z=tile[qq*8+2][b]; v0.w=tile[qq*8+3][b];
  v1.x=tile[qq*8+4][b]; v1.y=tile[qq*8+5][b]; v1.z=tile[qq*8+6][b]; v1.w=tile[qq*8+7][b];
  *(float4*)dst = v0;
  *(float4*)(dst+4) = v1;
}

// final LSTM (step 15's gates) -> h_16 to d_out. Block per b, thread = u.
__global__ __launch_bounds__(512) void final_k(
    const float* __restrict__ partT, // [NCHUNK][NB][NGATES]
    const float* __restrict__ b_ih, const float* __restrict__ b_hh,
    const float* __restrict__ cbuf,
    float* __restrict__ out)         // [NB][CO]
{
  int b = blockIdx.x, u = threadIdx.x;
  float gi=0.f, gf=0.f, gc=0.f, go=0.f;
  #pragma unroll
  for (int s2=0; s2<NCHUNK; s2++){
    const float* p = partT + ((size_t)s2*NB + b)*NGATES;
    gi += p[u];
    gf += p[512+u];
    gc += p[1024+u];
    go += p[1536+u];
  }
  gi += b_ih[u]      + b_hh[u];
  gf += b_ih[512+u]  + b_hh[512+u];
  gc += b_ih[1024+u] + b_hh[1024+u];
  go += b_ih[1536+u] + b_hh[1536+u];
  float cold = cbuf[(size_t)1*NB*CO + (size_t)b*CO + u];  // c_15 (15&1==1)
  float cnew = sigmoidf_(gf)*cold + sigmoidf_(gi)*tanhf(gc);
  float hnew = sigmoidf_(go)*tanhf(cnew);
  out[(size_t)b*CO + u] = hnew;
}

extern "C" void kernel_launch(void* const* d_in, const int* in_sizes, int n_in,
                              void* d_out, int out_size, void* d_ws, size_t ws_size,
                              hipStream_t stream){
  const float* imgs = (const float*)d_in[0];
  const float* W_ih = (const float*)d_in[1];
  const float* W_hh = (const float*)d_in[2];
  const float* b_ih = (const float*)d_in[3];
  const float* b_hh = (const float*)d_in[4];
  const float* Wg   = (const float*)d_in[5];
  const float* bg   = (const float*)d_in[6];
  // d_in[7] = num_glimpses (always 8) -> 16 steps hardcoded.

  float* ws = (float*)d_ws;
  size_t off = 0;
  float* Wcat  = ws + off; off += (size_t)KTOT*NGATES;     // [1280][2048]
  float* xp0   = ws + off; off += (size_t)KTOT*NB;
  float* xp1   = ws + off; off += (size_t)KTOT*NB;
  float* partT = ws + off; off += (size_t)NCHUNK*NB*NGATES;
  float* cbuf  = ws + off; off += (size_t)2*NB*CO;
  float* outp  = (float*)d_out;

  transpose_k<<<dim3(INDIM/32, NGATES/32), dim3(32,8), 0, stream>>>(W_ih, Wcat, NGATES, INDIM);
  transpose_k<<<dim3(CO/32,    NGATES/32), dim3(32,8), 0, stream>>>(W_hh, Wcat + (size_t)INDIM*NGATES, NGATES, CO);

  for (int t=0; t<16; t++){
    extlstm5_k<<<NB*6, 512, 0, stream>>>(imgs, t, partT, b_ih, b_hh, Wg, bg, cbuf, xp0, xp1);
    gates6_k  <<<512,  256, 0, stream>>>(Wcat, xp0, xp1, partT);
  }
  final_k<<<NB, 512, 0, stream>>>(partT, b_ih, b_hh, cbuf, outp);
}